// Round 22
// baseline (114.889 us; speedup 1.0000x reference)
//
#include <hip/hip_runtime.h>
#include <math.h>

#define T_LEN   16384          // 4^7
#define NTH     512
#define TPRIME  64
#define NPATH   577            // 1 + 64 + 512
#define INV_T   (1.0f/16384.0f)
#define TWO_PI  6.28318530717958647692f
#define NW      640            // lowpass kernel half-width
#define NH      (NW + 1)
#define C8C     0.92387953251128675613f   // cos(pi/8)
#define C8S     0.38268343236508977173f   // sin(pi/8)

__device__ __forceinline__ int rev4(int i) {
    int r = 0;
#pragma unroll
    for (int p = 0; p < 7; ++p) { r = (r << 2) | (i & 3); i >>= 2; }
    return r;
}
__device__ __forceinline__ int IDX(int i) {
    return i ^ ((i >> 4) & 15) ^ ((i >> 8) & 15);
}
#define S6 IDX
__device__ __forceinline__ int UIDX(int n) {
    return n ^ ((n >> 5) & 31) ^ ((n >> 10) & 31);
}
__device__ __forceinline__ int US(int n) { return n ^ ((n >> 5) & 31); }

// ---------------- butterflies (identical math since R3) --------------------
__device__ __forceinline__ void inv_bf4(float2& A0, float2& A1, float2& A2, float2& A3,
                                        float c1, float s1) {
    float sr = A0.x + A1.x + A2.x + A3.x, si = A0.y + A1.y + A2.y + A3.y;
    float tr = A0.x - A1.y - A2.x + A3.y, ti = A0.y + A1.x - A2.y - A3.x;
    float ur = A0.x - A1.x + A2.x - A3.x, ui = A0.y - A1.y + A2.y - A3.y;
    float vr = A0.x + A1.y - A2.x - A3.y, vi = A0.y - A1.x - A2.y + A3.x;
    float c2 = c1*c1 - s1*s1, s2 = 2.f*c1*s1;
    float c3 = c1*c2 - s1*s2, s3 = c1*s2 + s1*c2;
    A0 = make_float2(sr, si);
    A1 = make_float2(tr*c1 - ti*s1, tr*s1 + ti*c1);
    A2 = make_float2(ur*c2 - ui*s2, ur*s2 + ui*c2);
    A3 = make_float2(vr*c3 - vi*s3, vr*s3 + vi*c3);
}
__device__ __forceinline__ void fwd_bf4(float2& B0, float2& B1, float2& B2, float2& B3,
                                        float c1, float s1) {
    float c2 = c1*c1 - s1*s1, s2 = 2.f*c1*s1;
    float c3 = c1*c2 - s1*s2, s3 = c1*s2 + s1*c2;
    float trr = B1.x*c1 + B1.y*s1, tii = B1.y*c1 - B1.x*s1;
    float urr = B2.x*c2 + B2.y*s2, uii = B2.y*c2 - B2.x*s2;
    float vrr = B3.x*c3 + B3.y*s3, vii = B3.y*c3 - B3.x*s3;
    float s0r = B0.x, s0i = B0.y;
    B0 = make_float2(s0r + trr + urr + vrr, s0i + tii + uii + vii);
    B1 = make_float2(s0r + tii - urr - vii, s0i - trr - uii + vrr);
    B2 = make_float2(s0r - trr + urr - vrr, s0i - tii + uii - vii);
    B3 = make_float2(s0r - tii - urr + vii, s0i + trr - uii - vrr);
}

template<int Q>
__device__ __forceinline__ void inv_group16(float2* v, int jp) {
    float a0 = (float)jp * (TWO_PI / (float)(4 * Q));
    float cw, sw; __sincosf(a0, &sw, &cw);
    float c = cw, s = sw;
#pragma unroll
    for (int rp = 0; rp < 4; ++rp) {
        inv_bf4(v[rp], v[4+rp], v[8+rp], v[12+rp], c, s);
        float cn = c*C8C - s*C8S, sn = c*C8S + s*C8C;
        c = cn; s = sn;
    }
    float b0 = (float)jp * (TWO_PI / (float)Q);
    float cb, sb; __sincosf(b0, &sb, &cb);
#pragma unroll
    for (int r = 0; r < 4; ++r)
        inv_bf4(v[4*r], v[4*r+1], v[4*r+2], v[4*r+3], cb, sb);
}
template<int QA>
__device__ __forceinline__ void fwd_group16(float2* v, int jp) {
    float aA = (float)jp * (TWO_PI / (float)(4 * QA));
    float cA, sA; __sincosf(aA, &sA, &cA);
#pragma unroll
    for (int r = 0; r < 4; ++r)
        fwd_bf4(v[4*r], v[4*r+1], v[4*r+2], v[4*r+3], cA, sA);
    float aB = (float)jp * (TWO_PI / (float)(16 * QA));
    float cB, sB; __sincosf(aB, &sB, &cB);
    float c = cB, s = sB;
#pragma unroll
    for (int rp = 0; rp < 4; ++rp) {
        fwd_bf4(v[rp], v[4+rp], v[8+rp], v[12+rp], c, s);
        float cn = c*C8C - s*C8S, sn = c*C8S + s*C8C;
        c = cn; s = sn;
    }
}

// ======================= K1: pass_a L12 + hconv ============================
__global__ __launch_bounds__(512) void k1_prep(const float* __restrict__ x,
                                               const float* __restrict__ phi,
                                               float2* __restrict__ Z,
                                               float* __restrict__ hws,
                                               int B2) {
    const int bi = blockIdx.x;
    if (bi < B2) {
        const int b = bi >> 1;
        const int jp = ((bi & 1) << 9) | threadIdx.x;   // 0..1023
        const float* xb = x + (size_t)b * T_LEN;
        float2* Zb = Z + (size_t)b * T_LEN;
        float2 v[16];
#pragma unroll
        for (int r = 0; r < 4; ++r)
#pragma unroll
            for (int rp = 0; rp < 4; ++rp)
                v[4*r+rp] = make_float2(xb[jp + r*4096 + rp*1024], 0.f);
        inv_group16<4096>(v, jp);
#pragma unroll
        for (int r = 0; r < 4; ++r)
#pragma unroll
            for (int rp = 0; rp < 4; ++rp)
                Zb[jp + r*4096 + rp*1024] = v[4*r+rp];
    } else {
        const int d = (bi - B2) * 8 + (threadIdx.x >> 6);
        const int l = threadIdx.x & 63;
        float p = 0.f;
#pragma unroll
        for (int j = 0; j < 8; ++j) {
            int w = l + 64 * j;                   // 0..511
            int k = (w < 256) ? w : (15872 + w);  // [0,255] U [16128,16383]
            int r = (k * d) & (T_LEN - 1);
            p += phi[k] * __cosf((float)r * (TWO_PI / (float)T_LEN));
        }
        p += __shfl_xor(p, 1);  p += __shfl_xor(p, 2);  p += __shfl_xor(p, 4);
        p += __shfl_xor(p, 8);  p += __shfl_xor(p, 16); p += __shfl_xor(p, 32);
        if (l == 0 && d <= NW) hws[d] = p * INV_T;
    }
}

// ================= K2: pass_a chunk tails + S0 =============================
__global__ __launch_bounds__(256) void k2_chunk_s0(const float2* __restrict__ Z,
                                                   const float* __restrict__ x,
                                                   const float* __restrict__ hws,
                                                   float2* __restrict__ wsX,
                                                   float* __restrict__ out,
                                                   int B4) {
    __shared__ float2 lds[4096];
    __shared__ float hl[NH];
    const int bi = blockIdx.x;
    if (bi < B4) {
        const int b = bi >> 2;
        const int c0 = (bi & 3) << 12;
        const float2* Zb = Z + (size_t)b * T_LEN + c0;
        for (int i = threadIdx.x; i < 4096; i += 256) lds[IDX(i)] = Zb[i];
        {
            __syncthreads();
            int g = threadIdx.x;
            int jp = g & 63, base = ((g >> 6) << 10) | jp;
            float2 v[16];
#pragma unroll
            for (int r = 0; r < 4; ++r)
#pragma unroll
                for (int rp = 0; rp < 4; ++rp)
                    v[4*r+rp] = lds[IDX(base + r*256 + rp*64)];
            inv_group16<256>(v, jp);
#pragma unroll
            for (int r = 0; r < 4; ++r)
#pragma unroll
                for (int rp = 0; rp < 4; ++rp)
                    lds[IDX(base + r*256 + rp*64)] = v[4*r+rp];
        }
        {
            __syncthreads();
            int g = threadIdx.x;
            int jp = g & 3, base = ((g >> 2) << 6) | jp;
            float2 v[16];
#pragma unroll
            for (int r = 0; r < 4; ++r)
#pragma unroll
                for (int rp = 0; rp < 4; ++rp)
                    v[4*r+rp] = lds[IDX(base + r*16 + rp*4)];
            inv_group16<16>(v, jp);
#pragma unroll
            for (int r = 0; r < 4; ++r)
#pragma unroll
                for (int rp = 0; rp < 4; ++rp)
                    lds[IDX(base + r*16 + rp*4)] = v[4*r+rp];
        }
        __syncthreads();
        float2* W = wsX + (size_t)b * T_LEN;
#pragma unroll
        for (int it = 0; it < 4; ++it) {
            int bl = (threadIdx.x + it * 256) << 2;
            float2 a0 = lds[IDX(bl)], a1 = lds[IDX(bl+1)], a2 = lds[IDX(bl+2)], a3 = lds[IDX(bl+3)];
            inv_bf4(a0, a1, a2, a3, 1.0f, 0.0f);
            int rb = rev4(c0 + bl);
            W[rb]         = make_float2(a0.x, -a0.y);
            W[rb + 4096]  = make_float2(a1.x, -a1.y);
            W[rb + 8192]  = make_float2(a2.x, -a2.y);
            W[rb + 12288] = make_float2(a3.x, -a3.y);
        }
    } else {
        const int q = bi - B4;
        const int b = q >> 3;
        const int m0 = (q & 7) << 3;
        for (int i = threadIdx.x; i < NH; i += 256) hl[i] = hws[i];
        __syncthreads();
        const float* xb = x + (size_t)b * T_LEN;
        const int m = m0 + (threadIdx.x >> 5);
        const int s = threadIdx.x & 31;
        const int c = m << 8;
        float acc = 0.f;
        for (int e = -NW + s; e <= NW; e += 32) {
            int n = (c + e) & (T_LEN - 1);
            int a = e < 0 ? -e : e;
            acc += hl[a] * xb[n];
        }
        acc += __shfl_xor(acc, 1);  acc += __shfl_xor(acc, 2);
        acc += __shfl_xor(acc, 4);  acc += __shfl_xor(acc, 8);
        acc += __shfl_xor(acc, 16);
        if (s == 0) out[(size_t)b * (NPATH * TPRIME) + m] = acc;
    }
}

// ========== KB1: pass_b stage 1 — inv L12, registers, windowed =============
__global__ __launch_bounds__(512) void kb1(const float2* __restrict__ wsX,
                                           const float* __restrict__ psi1,
                                           float2* __restrict__ wsU) {
    const int path = blockIdx.x >> 1, half = blockIdx.x & 1;
    const int b = path >> 6, n1 = path & 63;
    const int jp = (half << 9) | threadIdx.x;   // 0..1023
    float xi1T = 5734.4f * exp2f(-(float)n1 / 8.0f);
    int clo = (int)(0.40f * xi1T) >> 10;
    int chi = ((int)(1.60f * xi1T)) >> 10; if (chi > 15) chi = 15;
    const float2* Xb = wsX + (size_t)b * T_LEN;
    const float* ps = psi1 + (size_t)n1 * T_LEN;
    float2 v[16];
#pragma unroll
    for (int r = 0; r < 4; ++r)
#pragma unroll
        for (int rp = 0; rp < 4; ++rp) {
            int ch = 4*r + rp;
            if (ch >= clo && ch <= chi) {
                int i = jp + r*4096 + rp*1024;
                float2 a = Xb[i]; float p = ps[i];
                v[4*r+rp] = make_float2(a.x*p, a.y*p);
            } else {
                v[4*r+rp] = make_float2(0.f, 0.f);
            }
        }
    inv_group16<4096>(v, jp);
    float2* Zr = wsU + (size_t)path * T_LEN;
#pragma unroll
    for (int r = 0; r < 4; ++r)
#pragma unroll
        for (int rp = 0; rp < 4; ++rp)
            Zr[jp + r*4096 + rp*1024] = v[4*r+rp];
}

// ========== KB2: pass_b stage 2 — chunk-local inv tail + mod + fwd head ====
__global__ __launch_bounds__(256) void kb2(float2* __restrict__ wsU) {
    __shared__ float2 lds[4096];
    const int path = blockIdx.x >> 2, c0 = (blockIdx.x & 3) << 12;
    const int t = threadIdx.x;
    float2* Zr = wsU + (size_t)path * T_LEN + c0;
    for (int i = t; i < 4096; i += 256) lds[IDX(i)] = Zr[i];
    {   // inv merged q=256,64
        __syncthreads();
        int jp = t & 63, base = ((t >> 6) << 10) | jp;
        float2 v[16];
#pragma unroll
        for (int r = 0; r < 4; ++r)
#pragma unroll
            for (int rp = 0; rp < 4; ++rp)
                v[4*r+rp] = lds[IDX(base + r*256 + rp*64)];
        inv_group16<256>(v, jp);
#pragma unroll
        for (int r = 0; r < 4; ++r)
#pragma unroll
            for (int rp = 0; rp < 4; ++rp)
                lds[IDX(base + r*256 + rp*64)] = v[4*r+rp];
    }
    {   // inv merged q=16,4
        __syncthreads();
        int jp = t & 3, base = ((t >> 2) << 6) | jp;
        float2 v[16];
#pragma unroll
        for (int r = 0; r < 4; ++r)
#pragma unroll
            for (int rp = 0; rp < 4; ++rp)
                v[4*r+rp] = lds[IDX(base + r*16 + rp*4)];
        inv_group16<16>(v, jp);
#pragma unroll
        for (int r = 0; r < 4; ++r)
#pragma unroll
            for (int rp = 0; rp < 4; ++rp)
                lds[IDX(base + r*16 + rp*4)] = v[4*r+rp];
    }
    __syncthreads();
    // final inv q=1 + modulus + first fwd q=1 (quadruplet-local)
#pragma unroll
    for (int it = 0; it < 4; ++it) {
        int bl = (t + it * 256) << 2;
        float2 a0 = lds[IDX(bl)], a1 = lds[IDX(bl+1)], a2 = lds[IDX(bl+2)], a3 = lds[IDX(bl+3)];
        inv_bf4(a0, a1, a2, a3, 1.0f, 0.0f);
        float2 b0 = make_float2(sqrtf(a0.x*a0.x + a0.y*a0.y) * INV_T, 0.f);
        float2 b1 = make_float2(sqrtf(a1.x*a1.x + a1.y*a1.y) * INV_T, 0.f);
        float2 b2 = make_float2(sqrtf(a2.x*a2.x + a2.y*a2.y) * INV_T, 0.f);
        float2 b3 = make_float2(sqrtf(a3.x*a3.x + a3.y*a3.y) * INV_T, 0.f);
        fwd_bf4(b0, b1, b2, b3, 1.0f, 0.0f);
        lds[IDX(bl)] = b0; lds[IDX(bl+1)] = b1; lds[IDX(bl+2)] = b2; lds[IDX(bl+3)] = b3;
    }
    {   // fwd merged q=4,16  (slots base + r*16 + rp*4, qA=4)
        __syncthreads();
        int jp = t & 3, base = ((t >> 2) << 6) | jp;
        float2 v[16];
#pragma unroll
        for (int r = 0; r < 4; ++r)
#pragma unroll
            for (int rp = 0; rp < 4; ++rp)
                v[4*r+rp] = lds[IDX(base + r*16 + rp*4)];
        fwd_group16<4>(v, jp);
#pragma unroll
        for (int r = 0; r < 4; ++r)
#pragma unroll
            for (int rp = 0; rp < 4; ++rp)
                lds[IDX(base + r*16 + rp*4)] = v[4*r+rp];
    }
    {   // fwd merged q=64,256 (R22 FIX: slots base + r*256 + rp*64, qA=64;
        // R21 wrongly used r*64 + rp*16 -> wrong butterflies -> absmax 0.287)
        __syncthreads();
        int jp = t & 63, base = ((t >> 6) << 10) | jp;
        float2 v[16];
#pragma unroll
        for (int r = 0; r < 4; ++r)
#pragma unroll
            for (int rp = 0; rp < 4; ++rp)
                v[4*r+rp] = lds[IDX(base + r*256 + rp*64)];
        fwd_group16<64>(v, jp);
#pragma unroll
        for (int r = 0; r < 4; ++r)
#pragma unroll
            for (int rp = 0; rp < 4; ++rp)
                lds[IDX(base + r*256 + rp*64)] = v[4*r+rp];
    }
    __syncthreads();
    for (int i = t; i < 4096; i += 256) Zr[i] = lds[IDX(i)];
}

// ========== KB3: pass_b stage 3 — fwd L10 (registers) + zs + S1 ============
__global__ __launch_bounds__(512) void kb3(float2* __restrict__ wsU,
                                           const float* __restrict__ phi,
                                           float* __restrict__ out) {
    __shared__ float2 zs[128];
    const int path = blockIdx.x >> 1, half = blockIdx.x & 1;
    const int b = path >> 6, n1 = path & 63;
    const int t = threadIdx.x;
    const int n2min = (n1 >> 3) + 1;
    int nch = 0;
    if (n2min <= 7) {
        int S = 24084 >> n2min;
        nch = (S >> 10) + 1; if (nch > 10) nch = 10;
    }
    if (half == 1 && nch == 0) return;      // nothing to store, S1 in half 0
    const int jp = (half << 9) | t;
    float2* Zr = wsU + (size_t)path * T_LEN;
    float2 v[16];
#pragma unroll
    for (int r = 0; r < 4; ++r)
#pragma unroll
        for (int rp = 0; rp < 4; ++rp)
            v[4*r+rp] = Zr[jp + r*4096 + rp*1024];
    fwd_group16<1024>(v, jp);
    if (half == 0 && jp < 124) zs[jp] = v[0];   // bin k = jp (r=rp=0)
#pragma unroll
    for (int r = 0; r < 4; ++r)
#pragma unroll
        for (int rp = 0; rp < 4; ++rp) {
            int ch = 4*r + rp;
            if (ch < nch)
                Zr[jp + r*4096 + rp*1024] = v[4*r+rp];
        }
    if (half != 0) return;
    __syncthreads();
    // S1[m] = (1/T)(U1h[0]phi[0] + 2 sum_{k=1..123} Re(U1h[k] phi[k] e^{2pi i km/64}))
    const int m = t >> 3;
    const int s = t & 7;
    float acc = 0.f;
    for (int k = 1 + s; k < 124; k += 8) {
        float ph = phi[k];
        float2 z = zs[k];
        float ang = (float)((k * m) & 63) * (TWO_PI / 64.0f);
        float sn, cs; __sincosf(ang, &sn, &cs);
        acc += 2.0f * ph * (z.x * cs - z.y * sn);
    }
    acc += __shfl_xor(acc, 1);
    acc += __shfl_xor(acc, 2);
    acc += __shfl_xor(acc, 4);
    if (s == 0) {
        acc += zs[0].x * phi[0];
        out[(size_t)b * (NPATH * TPRIME) + (size_t)(1 + n1) * TPRIME + m] = acc * INV_T;
    }
}

// ====== K4a: med (n2 in {1,2}), 512 threads, h-halves IN PARALLEL ==========
__global__ __launch_bounds__(512) void k4_med2(const float2* __restrict__ wsU,
                                               const float* __restrict__ psi2,
                                               const float* __restrict__ hws,
                                               float* __restrict__ out) {
    __shared__ float2 sc2[8192];    // 64 KB: two 4096-slot halves
    __shared__ float h2s[321];
    const int tj = threadIdx.x;
    const int hh = tj >> 8, t = tj & 255;
    const int idx = blockIdx.x % 24, b = blockIdx.x / 24;
    const int n2 = (idx < 8) ? 1 : 2;
    const int n1 = (idx < 8) ? idx : idx - 8;
    for (int i = tj; i < 321; i += 512) h2s[i] = 2.0f * hws[2 * i];
    float2* sc = sc2 + (hh << 12);
    const float2* Ub = wsU + (size_t)((b << 6) | n1) * T_LEN;
    const float* p2 = psi2 + (size_t)n2 * T_LEN;
    const int lim = (n2 == 1) ? 10240 : 6144;
    float2 v[16];
#pragma unroll
    for (int r = 0; r < 4; ++r) {
#pragma unroll
        for (int rp = 0; rp < 4; ++rp) {
            int i = t + r*1024 + rp*256;
            float2 y0 = Ub[i]; float q0 = p2[i];
            float ar = y0.x * q0, ai = y0.y * q0;
            if (i + 4096 < lim) {
                float2 y1 = Ub[i + 4096]; float q1 = p2[i + 4096];
                if (hh == 0) { ar += y1.x*q1; ai += y1.y*q1; }
                else         { ar -= y1.x*q1; ai -= y1.y*q1; }
            }
            if (i + 8192 < lim) {
                float2 y2 = Ub[i + 8192]; float q2 = p2[i + 8192];
                ar += y2.x*q2; ai += y2.y*q2;
            }
            if (hh == 1) {  // twiddle e^{+2 pi i j / 8192}
                float ang = (float)i * (TWO_PI / 8192.0f);
                float sn, cs; __sincosf(ang, &sn, &cs);
                float nr = ar*cs - ai*sn, ni = ar*sn + ai*cs;
                ar = nr; ai = ni;
            }
            v[4*r+rp] = make_float2(ar, ai);
        }
        asm volatile("" ::: "memory");
    }
    inv_group16<1024>(v, t);
#pragma unroll
    for (int r = 0; r < 4; ++r)
#pragma unroll
        for (int rp = 0; rp < 4; ++rp)
            sc[S6(t + r*1024 + rp*256)] = v[4*r+rp];
    __syncthreads();
    {
        int jp = t & 15, base = ((t >> 4) << 8) | jp;
#pragma unroll
        for (int r = 0; r < 4; ++r)
#pragma unroll
            for (int rp = 0; rp < 4; ++rp)
                v[4*r+rp] = sc[S6(base + r*64 + rp*16)];
        inv_group16<64>(v, jp);
#pragma unroll
        for (int r = 0; r < 4; ++r)
#pragma unroll
            for (int rp = 0; rp < 4; ++rp)
                sc[S6(base + r*64 + rp*16)] = v[4*r+rp];
    }
    __syncthreads();
    float mg[16];
    {
        int base = t << 4;
#pragma unroll
        for (int r = 0; r < 4; ++r)
#pragma unroll
            for (int rp = 0; rp < 4; ++rp)
                v[4*r+rp] = sc[S6(base + 4*r + rp)];
        inv_group16<4>(v, 0);
#pragma unroll
        for (int k = 0; k < 16; ++k)
            mg[k] = sqrtf(v[k].x*v[k].x + v[k].y*v[k].y) * INV_T;
    }
    __syncthreads();    // all sc reads done before float reuse
    float* u8s = (float*)sc2;   // first 32 KB of sc2 (8192 floats)
    int rt = ((t & 3) << 6) | (((t >> 2) & 3) << 4) | (((t >> 4) & 3) << 2) | (t >> 6);
#pragma unroll
    for (int r = 0; r < 4; ++r)
#pragma unroll
        for (int rp = 0; rp < 4; ++rp) {
            int pos = rp*1024 + r*256 + rt;
            u8s[UIDX(2 * pos + hh)] = mg[4*r+rp];
        }
    __syncthreads();
    // lowpass on 8192 (stride-2) grid: 8 lanes per output
    const int m = tj >> 3, s = tj & 7;
    float acc = 0.f;
    for (int e = -320 + s; e <= 320; e += 8) {
        int n = (128*m + e) & 8191;
        int a = e < 0 ? -e : e;
        acc += h2s[a] * u8s[UIDX(n)];
    }
    acc += __shfl_xor(acc, 1);
    acc += __shfl_xor(acc, 2);
    acc += __shfl_xor(acc, 4);
    if (s == 0)
        out[(size_t)b * (NPATH * TPRIME) + (size_t)(65 + (n1 << 3) + n2) * TPRIME + m] = acc;
}

// ======= K4b: small (n2>=3, 200/batch) + zero-invalid (288/batch) ==========
__global__ __launch_bounds__(256) void k4_small(const float2* __restrict__ wsU,
                                                const float* __restrict__ psi2,
                                                const float* __restrict__ hws,
                                                float* __restrict__ out) {
    __shared__ float2 buf[4096];
    __shared__ float hd[161];
    const int t = threadIdx.x;
    const int idx = blockIdx.x % 488, b = blockIdx.x / 488;

    if (idx >= 200) {               // ---- zero block: one invalid S2 path ----
        int z = idx - 200;          // 0..287
        int g = 0, cum = 0;
#pragma unroll
        for (int gg = 0; gg < 8; ++gg) {
            int c = 8 * (gg + 1);
            if (z >= cum + c) { cum += c; g = gg + 1; }
        }
        int zz = z - cum;
        int n1 = g * 8 + zz / (g + 1);
        int n2 = zz % (g + 1);
        if (t < TPRIME)
            out[(size_t)b * (NPATH * TPRIME) + (size_t)(65 + (n1 << 3) + n2) * TPRIME + t] = 0.f;
        return;
    }

    const int p = idx;
    int n1, n2;
    if      (p < 24)  { n2 = 3; n1 = p; }
    else if (p < 56)  { n2 = 4; n1 = p - 24; }
    else if (p < 96)  { n2 = 5; n1 = p - 56; }
    else if (p < 144) { n2 = 6; n1 = p - 96; }
    else              { n2 = 7; n1 = p - 144; }
    if (t < 161) hd[t] = 4.0f * hws[4 * t];
    const int kc = ((((int)(24084.0f * exp2f(-(float)n2))) >> 10) + 1) << 2;
    const float2* Ub = wsU + (size_t)((b << 6) | n1) * T_LEN;
    const float* p2 = psi2 + (size_t)n2 * T_LEN;
    float2 v[16];
#pragma unroll
    for (int r = 0; r < 4; ++r)
#pragma unroll
        for (int rp = 0; rp < 4; ++rp) {
            int ch = 4*r + rp;
            if (ch < kc) {
                int i = t + r*1024 + rp*256;
                float2 u = Ub[i]; float pp = p2[i];
                v[4*r+rp] = make_float2(u.x*pp, u.y*pp);
            } else {
                v[4*r+rp] = make_float2(0.f, 0.f);
            }
        }
    inv_group16<1024>(v, t);
#pragma unroll
    for (int r = 0; r < 4; ++r)
#pragma unroll
        for (int rp = 0; rp < 4; ++rp)
            buf[S6(t + r*1024 + rp*256)] = v[4*r+rp];
    __syncthreads();
    {
        int jp = t & 15, base = ((t >> 4) << 8) | jp;
#pragma unroll
        for (int r = 0; r < 4; ++r)
#pragma unroll
            for (int rp = 0; rp < 4; ++rp)
                v[4*r+rp] = buf[S6(base + r*64 + rp*16)];
        inv_group16<64>(v, jp);
#pragma unroll
        for (int r = 0; r < 4; ++r)
#pragma unroll
            for (int rp = 0; rp < 4; ++rp)
                buf[S6(base + r*64 + rp*16)] = v[4*r+rp];
    }
    __syncthreads();
    float mg[16];
    {
        int base = t << 4;
#pragma unroll
        for (int r = 0; r < 4; ++r)
#pragma unroll
            for (int rp = 0; rp < 4; ++rp)
                v[4*r+rp] = buf[S6(base + 4*r + rp)];
        inv_group16<4>(v, 0);
#pragma unroll
        for (int k = 0; k < 16; ++k)
            mg[k] = sqrtf(v[k].x*v[k].x + v[k].y*v[k].y) * INV_T;
    }
    __syncthreads();
    float* uf = (float*)buf;
    int rt = ((t & 3) << 6) | (((t >> 2) & 3) << 4) | (((t >> 4) & 3) << 2) | (t >> 6);
#pragma unroll
    for (int r = 0; r < 4; ++r)
#pragma unroll
        for (int rp = 0; rp < 4; ++rp)
            uf[US(rp*1024 + r*256 + rt)] = mg[4*r+rp];
    __syncthreads();
    const int m = t >> 2, s = t & 3;
    float acc = 0.f;
    for (int e = -160 + s; e <= 160; e += 4) {
        int n = (64*m + e) & 4095;
        int a = e < 0 ? -e : e;
        acc += hd[a] * uf[US(n)];
    }
    acc += __shfl_xor(acc, 1);
    acc += __shfl_xor(acc, 2);
    if (s == 0)
        out[(size_t)b * (NPATH * TPRIME) + (size_t)(65 + (n1 << 3) + n2) * TPRIME + m] = acc;
}

extern "C" void kernel_launch(void* const* d_in, const int* in_sizes, int n_in,
                              void* d_out, int out_size, void* d_ws, size_t ws_size,
                              hipStream_t stream) {
    const float* x    = (const float*)d_in[0];
    const float* psi1 = (const float*)d_in[1];
    const float* psi2 = (const float*)d_in[2];
    const float* phi  = (const float*)d_in[3];
    float* out = (float*)d_out;

    const int B = in_sizes[0] / T_LEN;          // 4

    float*  hws = (float*)d_ws;                               // NH floats (pad 4 KiB)
    float2* wsX = (float2*)((char*)d_ws + 4096);
    float2* wsU = (float2*)((char*)d_ws + 4096 + (size_t)B * T_LEN * sizeof(float2));
    float2* Z   = wsU;   // K1 intermediate; clobbered later by kb1 (stream-ordered)

    k1_prep<<<2 * B + 81, 512, 0, stream>>>(x, phi, Z, hws, 2 * B);
    k2_chunk_s0<<<4 * B + 8 * B, 256, 0, stream>>>(Z, x, hws, wsX, out, 4 * B);
    kb1<<<B * 128, 512, 0, stream>>>(wsX, psi1, wsU);
    kb2<<<B * 256, 256, 0, stream>>>(wsU);
    kb3<<<B * 128, 512, 0, stream>>>(wsU, phi, out);
    k4_med2<<<B * 24, 512, 0, stream>>>(wsU, psi2, hws, out);
    k4_small<<<B * 488, 256, 0, stream>>>(wsU, psi2, hws, out);
}

// Round 23
// 91.515 us; speedup vs baseline: 1.2554x; 1.2554x over previous
//
#include <hip/hip_runtime.h>
#include <math.h>

#define T_LEN   16384          // 4^7
#define NTH     512
#define TPRIME  64
#define NPATH   577            // 1 + 64 + 512
#define INV_T   (1.0f/16384.0f)
#define TWO_PI  6.28318530717958647692f
#define NW      640            // lowpass kernel half-width
#define NH      (NW + 1)
#define C8C     0.92387953251128675613f   // cos(pi/8)
#define C8S     0.38268343236508977173f   // sin(pi/8)

__device__ __forceinline__ int rev4(int i) {
    int r = 0;
#pragma unroll
    for (int p = 0; p < 7; ++p) { r = (r << 2) | (i & 3); i >>= 2; }
    return r;
}
__device__ __forceinline__ int IDX(int i) {
    return i ^ ((i >> 4) & 15) ^ ((i >> 8) & 15);
}
#define S6 IDX
__device__ __forceinline__ int UIDX(int n) {
    return n ^ ((n >> 5) & 31) ^ ((n >> 10) & 31);
}
__device__ __forceinline__ int US(int n) { return n ^ ((n >> 5) & 31); }

// ---------------- butterflies (identical math since R3) --------------------
__device__ __forceinline__ void inv_bf4(float2& A0, float2& A1, float2& A2, float2& A3,
                                        float c1, float s1) {
    float sr = A0.x + A1.x + A2.x + A3.x, si = A0.y + A1.y + A2.y + A3.y;
    float tr = A0.x - A1.y - A2.x + A3.y, ti = A0.y + A1.x - A2.y - A3.x;
    float ur = A0.x - A1.x + A2.x - A3.x, ui = A0.y - A1.y + A2.y - A3.y;
    float vr = A0.x + A1.y - A2.x - A3.y, vi = A0.y - A1.x - A2.y + A3.x;
    float c2 = c1*c1 - s1*s1, s2 = 2.f*c1*s1;
    float c3 = c1*c2 - s1*s2, s3 = c1*s2 + s1*c2;
    A0 = make_float2(sr, si);
    A1 = make_float2(tr*c1 - ti*s1, tr*s1 + ti*c1);
    A2 = make_float2(ur*c2 - ui*s2, ur*s2 + ui*c2);
    A3 = make_float2(vr*c3 - vi*s3, vr*s3 + vi*c3);
}
__device__ __forceinline__ void fwd_bf4(float2& B0, float2& B1, float2& B2, float2& B3,
                                        float c1, float s1) {
    float c2 = c1*c1 - s1*s1, s2 = 2.f*c1*s1;
    float c3 = c1*c2 - s1*s2, s3 = c1*s2 + s1*c2;
    float trr = B1.x*c1 + B1.y*s1, tii = B1.y*c1 - B1.x*s1;
    float urr = B2.x*c2 + B2.y*s2, uii = B2.y*c2 - B2.x*s2;
    float vrr = B3.x*c3 + B3.y*s3, vii = B3.y*c3 - B3.x*s3;
    float s0r = B0.x, s0i = B0.y;
    B0 = make_float2(s0r + trr + urr + vrr, s0i + tii + uii + vii);
    B1 = make_float2(s0r + tii - urr - vii, s0i - trr - uii + vrr);
    B2 = make_float2(s0r - trr + urr - vrr, s0i - tii + uii - vii);
    B3 = make_float2(s0r - tii - urr + vii, s0i + trr - uii - vrr);
}

template<int Q>
__device__ __forceinline__ void inv_group16(float2* v, int jp) {
    float a0 = (float)jp * (TWO_PI / (float)(4 * Q));
    float cw, sw; __sincosf(a0, &sw, &cw);
    float c = cw, s = sw;
#pragma unroll
    for (int rp = 0; rp < 4; ++rp) {
        inv_bf4(v[rp], v[4+rp], v[8+rp], v[12+rp], c, s);
        float cn = c*C8C - s*C8S, sn = c*C8S + s*C8C;
        c = cn; s = sn;
    }
    float b0 = (float)jp * (TWO_PI / (float)Q);
    float cb, sb; __sincosf(b0, &sb, &cb);
#pragma unroll
    for (int r = 0; r < 4; ++r)
        inv_bf4(v[4*r], v[4*r+1], v[4*r+2], v[4*r+3], cb, sb);
}
template<int QA>
__device__ __forceinline__ void fwd_group16(float2* v, int jp) {
    float aA = (float)jp * (TWO_PI / (float)(4 * QA));
    float cA, sA; __sincosf(aA, &sA, &cA);
#pragma unroll
    for (int r = 0; r < 4; ++r)
        fwd_bf4(v[4*r], v[4*r+1], v[4*r+2], v[4*r+3], cA, sA);
    float aB = (float)jp * (TWO_PI / (float)(16 * QA));
    float cB, sB; __sincosf(aB, &sB, &cB);
    float c = cB, s = sB;
#pragma unroll
    for (int rp = 0; rp < 4; ++rp) {
        fwd_bf4(v[rp], v[4+rp], v[8+rp], v[12+rp], c, s);
        float cn = c*C8C - s*C8S, sn = c*C8S + s*C8C;
        c = cn; s = sn;
    }
}

// ===== 512-thread merged passes, sequential groups (R10/R14-proven) ========
template<int LQ>
__device__ void inv_pass16(float2* buf) {
    const int q = 1 << LQ, qp = q >> 2;
    __syncthreads();
#pragma unroll
    for (int it = 0; it < 2; ++it) {
        int g2 = threadIdx.x + it * NTH;
        int jp = g2 & (qp - 1);
        int base = ((g2 >> (LQ - 2)) << (LQ + 2)) | jp;
        float2 v[16];
#pragma unroll
        for (int r = 0; r < 4; ++r)
#pragma unroll
            for (int rp = 0; rp < 4; ++rp)
                v[4*r+rp] = buf[IDX(base + r*q + rp*qp)];
        inv_group16<(1 << LQ)>(v, jp);
#pragma unroll
        for (int r = 0; r < 4; ++r)
#pragma unroll
            for (int rp = 0; rp < 4; ++rp)
                buf[IDX(base + r*q + rp*qp)] = v[4*r+rp];
    }
}

// merged inverse pass 0 (LQ=12), global src, windowed. R14: unroll 1 on the
// OUTER it-loop only (v declared inside, statically indexed -> registers).
__device__ void inv_pass16_g(const float2* __restrict__ src, const float* __restrict__ filt,
                             float2* buf, int clo, int chi) {
#pragma unroll 1
    for (int it = 0; it < 2; ++it) {
        int jp = threadIdx.x + it * NTH;
        float2 v[16];
#pragma unroll
        for (int r = 0; r < 4; ++r)
#pragma unroll
            for (int rp = 0; rp < 4; ++rp) {
                int ch = 4*r + rp;
                if (ch >= clo && ch <= chi) {
                    int i = jp + r*4096 + rp*1024;
                    float2 a = src[i]; float p = filt[i];
                    v[4*r+rp] = make_float2(a.x*p, a.y*p);
                } else {
                    v[4*r+rp] = make_float2(0.f, 0.f);
                }
            }
        inv_group16<4096>(v, jp);
#pragma unroll
        for (int r = 0; r < 4; ++r)
#pragma unroll
            for (int rp = 0; rp < 4; ++rp)
                buf[IDX(jp + r*4096 + rp*1024)] = v[4*r+rp];
        asm volatile("" ::: "memory");
    }
}

// FUSED: final inverse radix-4 + modulus + FIRST forward radix-4.
__device__ void mod_fwd4(float2* buf) {
    __syncthreads();
#pragma unroll
    for (int it = 0; it < 8; ++it) {
        int base = (threadIdx.x + it * NTH) << 2;
        float2 a0 = buf[IDX(base)], a1 = buf[IDX(base+1)], a2 = buf[IDX(base+2)], a3 = buf[IDX(base+3)];
        inv_bf4(a0, a1, a2, a3, 1.0f, 0.0f);
        float2 b0 = make_float2(sqrtf(a0.x*a0.x + a0.y*a0.y) * INV_T, 0.f);
        float2 b1 = make_float2(sqrtf(a1.x*a1.x + a1.y*a1.y) * INV_T, 0.f);
        float2 b2 = make_float2(sqrtf(a2.x*a2.x + a2.y*a2.y) * INV_T, 0.f);
        float2 b3 = make_float2(sqrtf(a3.x*a3.x + a3.y*a3.y) * INV_T, 0.f);
        fwd_bf4(b0, b1, b2, b3, 1.0f, 0.0f);
        buf[IDX(base)] = b0; buf[IDX(base+1)] = b1; buf[IDX(base+2)] = b2; buf[IDX(base+3)] = b3;
    }
}

template<int LQA>
__device__ void fwd_pass16(float2* buf) {
    const int qA = 1 << LQA, qB = 4 * qA;
    __syncthreads();
#pragma unroll
    for (int it = 0; it < 2; ++it) {
        int g2 = threadIdx.x + it * NTH;
        int jp = g2 & (qA - 1);
        int base = ((g2 >> LQA) << (LQA + 4)) | jp;
        float2 v[16];
#pragma unroll
        for (int r = 0; r < 4; ++r)
#pragma unroll
            for (int rp = 0; rp < 4; ++rp)
                v[4*r+rp] = buf[IDX(base + r*qB + rp*qA)];
        fwd_group16<(1 << LQA)>(v, jp);
#pragma unroll
        for (int r = 0; r < 4; ++r)
#pragma unroll
            for (int rp = 0; rp < 4; ++rp)
                buf[IDX(base + r*qB + rp*qA)] = v[4*r+rp];
    }
}

// last forward merged pass (LQA=10): windowed global store + zs staging
__device__ void fwd_last_store_zs(float2* buf, float2* __restrict__ gout, int nchunks,
                                  float2* zs) {
    __syncthreads();
#pragma unroll 1
    for (int it = 0; it < 2; ++it) {
        int jp = threadIdx.x + it * NTH;
        float2 v[16];
#pragma unroll
        for (int r = 0; r < 4; ++r)
#pragma unroll
            for (int rp = 0; rp < 4; ++rp)
                v[4*r+rp] = buf[IDX(jp + r*4096 + rp*1024)];
        fwd_group16<1024>(v, jp);
        if (it == 0 && jp < 124) zs[jp] = v[0];   // bin k = jp (r=rp=0)
#pragma unroll
        for (int r = 0; r < 4; ++r)
#pragma unroll
            for (int rp = 0; rp < 4; ++rp) {
                int ch = 4*r + rp;
                if (ch < nchunks)
                    gout[jp + r*4096 + rp*1024] = v[4*r+rp];
            }
        asm volatile("" ::: "memory");
    }
}

// ======================= K1: pass_a L12 + hconv ============================
__global__ __launch_bounds__(512) void k1_prep(const float* __restrict__ x,
                                               const float* __restrict__ phi,
                                               float2* __restrict__ Z,
                                               float* __restrict__ hws,
                                               int B2) {
    const int bi = blockIdx.x;
    if (bi < B2) {
        const int b = bi >> 1;
        const int jp = ((bi & 1) << 9) | threadIdx.x;   // 0..1023
        const float* xb = x + (size_t)b * T_LEN;
        float2* Zb = Z + (size_t)b * T_LEN;
        float2 v[16];
#pragma unroll
        for (int r = 0; r < 4; ++r)
#pragma unroll
            for (int rp = 0; rp < 4; ++rp)
                v[4*r+rp] = make_float2(xb[jp + r*4096 + rp*1024], 0.f);
        inv_group16<4096>(v, jp);
#pragma unroll
        for (int r = 0; r < 4; ++r)
#pragma unroll
            for (int rp = 0; rp < 4; ++rp)
                Zb[jp + r*4096 + rp*1024] = v[4*r+rp];
    } else {
        const int d = (bi - B2) * 8 + (threadIdx.x >> 6);
        const int l = threadIdx.x & 63;
        float p = 0.f;
#pragma unroll
        for (int j = 0; j < 8; ++j) {
            int w = l + 64 * j;                   // 0..511
            int k = (w < 256) ? w : (15872 + w);  // [0,255] U [16128,16383]
            int r = (k * d) & (T_LEN - 1);
            p += phi[k] * __cosf((float)r * (TWO_PI / (float)T_LEN));
        }
        p += __shfl_xor(p, 1);  p += __shfl_xor(p, 2);  p += __shfl_xor(p, 4);
        p += __shfl_xor(p, 8);  p += __shfl_xor(p, 16); p += __shfl_xor(p, 32);
        if (l == 0 && d <= NW) hws[d] = p * INV_T;
    }
}

// ================= K2: pass_a chunk tails + S0 =============================
__global__ __launch_bounds__(256) void k2_chunk_s0(const float2* __restrict__ Z,
                                                   const float* __restrict__ x,
                                                   const float* __restrict__ hws,
                                                   float2* __restrict__ wsX,
                                                   float* __restrict__ out,
                                                   int B4) {
    __shared__ float2 lds[4096];
    __shared__ float hl[NH];
    const int bi = blockIdx.x;
    if (bi < B4) {
        const int b = bi >> 2;
        const int c0 = (bi & 3) << 12;
        const float2* Zb = Z + (size_t)b * T_LEN + c0;
        for (int i = threadIdx.x; i < 4096; i += 256) lds[IDX(i)] = Zb[i];
        {
            __syncthreads();
            int g = threadIdx.x;
            int jp = g & 63, base = ((g >> 6) << 10) | jp;
            float2 v[16];
#pragma unroll
            for (int r = 0; r < 4; ++r)
#pragma unroll
                for (int rp = 0; rp < 4; ++rp)
                    v[4*r+rp] = lds[IDX(base + r*256 + rp*64)];
            inv_group16<256>(v, jp);
#pragma unroll
            for (int r = 0; r < 4; ++r)
#pragma unroll
                for (int rp = 0; rp < 4; ++rp)
                    lds[IDX(base + r*256 + rp*64)] = v[4*r+rp];
        }
        {
            __syncthreads();
            int g = threadIdx.x;
            int jp = g & 3, base = ((g >> 2) << 6) | jp;
            float2 v[16];
#pragma unroll
            for (int r = 0; r < 4; ++r)
#pragma unroll
                for (int rp = 0; rp < 4; ++rp)
                    v[4*r+rp] = lds[IDX(base + r*16 + rp*4)];
            inv_group16<16>(v, jp);
#pragma unroll
            for (int r = 0; r < 4; ++r)
#pragma unroll
                for (int rp = 0; rp < 4; ++rp)
                    lds[IDX(base + r*16 + rp*4)] = v[4*r+rp];
        }
        __syncthreads();
        float2* W = wsX + (size_t)b * T_LEN;
#pragma unroll
        for (int it = 0; it < 4; ++it) {
            int bl = (threadIdx.x + it * 256) << 2;
            float2 a0 = lds[IDX(bl)], a1 = lds[IDX(bl+1)], a2 = lds[IDX(bl+2)], a3 = lds[IDX(bl+3)];
            inv_bf4(a0, a1, a2, a3, 1.0f, 0.0f);
            int rb = rev4(c0 + bl);
            W[rb]         = make_float2(a0.x, -a0.y);
            W[rb + 4096]  = make_float2(a1.x, -a1.y);
            W[rb + 8192]  = make_float2(a2.x, -a2.y);
            W[rb + 12288] = make_float2(a3.x, -a3.y);
        }
    } else {
        const int q = bi - B4;
        const int b = q >> 3;
        const int m0 = (q & 7) << 3;
        for (int i = threadIdx.x; i < NH; i += 256) hl[i] = hws[i];
        __syncthreads();
        const float* xb = x + (size_t)b * T_LEN;
        const int m = m0 + (threadIdx.x >> 5);
        const int s = threadIdx.x & 31;
        const int c = m << 8;
        float acc = 0.f;
        for (int e = -NW + s; e <= NW; e += 32) {
            int n = (c + e) & (T_LEN - 1);
            int a = e < 0 ? -e : e;
            acc += hl[a] * xb[n];
        }
        acc += __shfl_xor(acc, 1);  acc += __shfl_xor(acc, 2);
        acc += __shfl_xor(acc, 4);  acc += __shfl_xor(acc, 8);
        acc += __shfl_xor(acc, 16);
        if (s == 0) out[(size_t)b * (NPATH * TPRIME) + m] = acc;
    }
}

// ================= K3: pass B (monolithic, R14-proven) =====================
__global__ __launch_bounds__(NTH)
__attribute__((amdgpu_waves_per_eu(1, 2)))
void pass_b(const float2* __restrict__ wsX,
            const float* __restrict__ psi1,
            const float* __restrict__ phi,
            float2* __restrict__ wsU,
            float* __restrict__ out) {
    __shared__ float2 buf[T_LEN];
    __shared__ float2 zs[128];
    const int blk = blockIdx.x;
    const int b = blk >> 6, n1 = blk & 63;
    float xi1T = 5734.4f * exp2f(-(float)n1 / 8.0f);
    int clo = (int)(0.40f * xi1T) >> 10;
    int chi = ((int)(1.60f * xi1T)) >> 10; if (chi > 15) chi = 15;
    inv_pass16_g(wsX + (size_t)b * T_LEN, psi1 + (size_t)n1 * T_LEN, buf, clo, chi);
    inv_pass16<8>(buf);
    inv_pass16<4>(buf);
    mod_fwd4(buf);
    fwd_pass16<2>(buf);
    fwd_pass16<6>(buf);
    const int n2min = (n1 >> 3) + 1;
    int nch = 0;
    if (n2min <= 7) {
        int S = 24084 >> n2min;
        nch = (S >> 10) + 1; if (nch > 10) nch = 10;
    }
    fwd_last_store_zs(buf, wsU + (size_t)blk * T_LEN, nch, zs);
    __syncthreads();
    const int m = threadIdx.x >> 3;
    const int s = threadIdx.x & 7;
    float acc = 0.f;
    for (int k = 1 + s; k < 124; k += 8) {
        float ph = phi[k];
        float2 z = zs[k];
        float ang = (float)((k * m) & 63) * (TWO_PI / 64.0f);
        float sn, cs; __sincosf(ang, &sn, &cs);
        acc += 2.0f * ph * (z.x * cs - z.y * sn);
    }
    acc += __shfl_xor(acc, 1);
    acc += __shfl_xor(acc, 2);
    acc += __shfl_xor(acc, 4);
    if (s == 0) {
        acc += zs[0].x * phi[0];
        out[(size_t)b * (NPATH * TPRIME) + (size_t)(1 + n1) * TPRIME + m] = acc * INV_T;
    }
}

// ====== K4a: med (n2 in {1,2}), 512 threads, h-halves IN PARALLEL ==========
__global__ __launch_bounds__(512) void k4_med2(const float2* __restrict__ wsU,
                                               const float* __restrict__ psi2,
                                               const float* __restrict__ hws,
                                               float* __restrict__ out) {
    __shared__ float2 sc2[8192];    // 64 KB: two 4096-slot halves
    __shared__ float h2s[321];
    const int tj = threadIdx.x;
    const int hh = tj >> 8, t = tj & 255;
    const int idx = blockIdx.x % 24, b = blockIdx.x / 24;
    const int n2 = (idx < 8) ? 1 : 2;
    const int n1 = (idx < 8) ? idx : idx - 8;
    for (int i = tj; i < 321; i += 512) h2s[i] = 2.0f * hws[2 * i];
    float2* sc = sc2 + (hh << 12);
    const float2* Ub = wsU + (size_t)((b << 6) | n1) * T_LEN;
    const float* p2 = psi2 + (size_t)n2 * T_LEN;
    const int lim = (n2 == 1) ? 10240 : 6144;
    float2 v[16];
#pragma unroll
    for (int r = 0; r < 4; ++r) {
#pragma unroll
        for (int rp = 0; rp < 4; ++rp) {
            int i = t + r*1024 + rp*256;
            float2 y0 = Ub[i]; float q0 = p2[i];
            float ar = y0.x * q0, ai = y0.y * q0;
            if (i + 4096 < lim) {
                float2 y1 = Ub[i + 4096]; float q1 = p2[i + 4096];
                if (hh == 0) { ar += y1.x*q1; ai += y1.y*q1; }
                else         { ar -= y1.x*q1; ai -= y1.y*q1; }
            }
            if (i + 8192 < lim) {
                float2 y2 = Ub[i + 8192]; float q2 = p2[i + 8192];
                ar += y2.x*q2; ai += y2.y*q2;
            }
            if (hh == 1) {  // twiddle e^{+2 pi i j / 8192}
                float ang = (float)i * (TWO_PI / 8192.0f);
                float sn, cs; __sincosf(ang, &sn, &cs);
                float nr = ar*cs - ai*sn, ni = ar*sn + ai*cs;
                ar = nr; ai = ni;
            }
            v[4*r+rp] = make_float2(ar, ai);
        }
        asm volatile("" ::: "memory");
    }
    inv_group16<1024>(v, t);
#pragma unroll
    for (int r = 0; r < 4; ++r)
#pragma unroll
        for (int rp = 0; rp < 4; ++rp)
            sc[S6(t + r*1024 + rp*256)] = v[4*r+rp];
    __syncthreads();
    {
        int jp = t & 15, base = ((t >> 4) << 8) | jp;
#pragma unroll
        for (int r = 0; r < 4; ++r)
#pragma unroll
            for (int rp = 0; rp < 4; ++rp)
                v[4*r+rp] = sc[S6(base + r*64 + rp*16)];
        inv_group16<64>(v, jp);
#pragma unroll
        for (int r = 0; r < 4; ++r)
#pragma unroll
            for (int rp = 0; rp < 4; ++rp)
                sc[S6(base + r*64 + rp*16)] = v[4*r+rp];
    }
    __syncthreads();
    float mg[16];
    {
        int base = t << 4;
#pragma unroll
        for (int r = 0; r < 4; ++r)
#pragma unroll
            for (int rp = 0; rp < 4; ++rp)
                v[4*r+rp] = sc[S6(base + 4*r + rp)];
        inv_group16<4>(v, 0);
#pragma unroll
        for (int k = 0; k < 16; ++k)
            mg[k] = sqrtf(v[k].x*v[k].x + v[k].y*v[k].y) * INV_T;
    }
    __syncthreads();    // all sc reads done before float reuse
    float* u8s = (float*)sc2;   // first 32 KB of sc2 (8192 floats)
    int rt = ((t & 3) << 6) | (((t >> 2) & 3) << 4) | (((t >> 4) & 3) << 2) | (t >> 6);
#pragma unroll
    for (int r = 0; r < 4; ++r)
#pragma unroll
        for (int rp = 0; rp < 4; ++rp) {
            int pos = rp*1024 + r*256 + rt;
            u8s[UIDX(2 * pos + hh)] = mg[4*r+rp];
        }
    __syncthreads();
    // lowpass on 8192 (stride-2) grid: 8 lanes per output
    const int m = tj >> 3, s = tj & 7;
    float acc = 0.f;
    for (int e = -320 + s; e <= 320; e += 8) {
        int n = (128*m + e) & 8191;
        int a = e < 0 ? -e : e;
        acc += h2s[a] * u8s[UIDX(n)];
    }
    acc += __shfl_xor(acc, 1);
    acc += __shfl_xor(acc, 2);
    acc += __shfl_xor(acc, 4);
    if (s == 0)
        out[(size_t)b * (NPATH * TPRIME) + (size_t)(65 + (n1 << 3) + n2) * TPRIME + m] = acc;
}

// ======= K4b: small (n2>=3, 200/batch) + zero-invalid (288/batch) ==========
__global__ __launch_bounds__(256) void k4_small(const float2* __restrict__ wsU,
                                                const float* __restrict__ psi2,
                                                const float* __restrict__ hws,
                                                float* __restrict__ out) {
    __shared__ float2 buf[4096];
    __shared__ float hd[161];
    const int t = threadIdx.x;
    const int idx = blockIdx.x % 488, b = blockIdx.x / 488;

    if (idx >= 200) {               // ---- zero block: one invalid S2 path ----
        int z = idx - 200;          // 0..287
        int g = 0, cum = 0;
#pragma unroll
        for (int gg = 0; gg < 8; ++gg) {
            int c = 8 * (gg + 1);
            if (z >= cum + c) { cum += c; g = gg + 1; }
        }
        int zz = z - cum;
        int n1 = g * 8 + zz / (g + 1);
        int n2 = zz % (g + 1);
        if (t < TPRIME)
            out[(size_t)b * (NPATH * TPRIME) + (size_t)(65 + (n1 << 3) + n2) * TPRIME + t] = 0.f;
        return;
    }

    const int p = idx;
    int n1, n2;
    if      (p < 24)  { n2 = 3; n1 = p; }
    else if (p < 56)  { n2 = 4; n1 = p - 24; }
    else if (p < 96)  { n2 = 5; n1 = p - 56; }
    else if (p < 144) { n2 = 6; n1 = p - 96; }
    else              { n2 = 7; n1 = p - 144; }
    if (t < 161) hd[t] = 4.0f * hws[4 * t];
    const int kc = ((((int)(24084.0f * exp2f(-(float)n2))) >> 10) + 1) << 2;
    const float2* Ub = wsU + (size_t)((b << 6) | n1) * T_LEN;
    const float* p2 = psi2 + (size_t)n2 * T_LEN;
    float2 v[16];
#pragma unroll
    for (int r = 0; r < 4; ++r)
#pragma unroll
        for (int rp = 0; rp < 4; ++rp) {
            int ch = 4*r + rp;
            if (ch < kc) {
                int i = t + r*1024 + rp*256;
                float2 u = Ub[i]; float pp = p2[i];
                v[4*r+rp] = make_float2(u.x*pp, u.y*pp);
            } else {
                v[4*r+rp] = make_float2(0.f, 0.f);
            }
        }
    inv_group16<1024>(v, t);
#pragma unroll
    for (int r = 0; r < 4; ++r)
#pragma unroll
        for (int rp = 0; rp < 4; ++rp)
            buf[S6(t + r*1024 + rp*256)] = v[4*r+rp];
    __syncthreads();
    {
        int jp = t & 15, base = ((t >> 4) << 8) | jp;
#pragma unroll
        for (int r = 0; r < 4; ++r)
#pragma unroll
            for (int rp = 0; rp < 4; ++rp)
                v[4*r+rp] = buf[S6(base + r*64 + rp*16)];
        inv_group16<64>(v, jp);
#pragma unroll
        for (int r = 0; r < 4; ++r)
#pragma unroll
            for (int rp = 0; rp < 4; ++rp)
                buf[S6(base + r*64 + rp*16)] = v[4*r+rp];
    }
    __syncthreads();
    float mg[16];
    {
        int base = t << 4;
#pragma unroll
        for (int r = 0; r < 4; ++r)
#pragma unroll
            for (int rp = 0; rp < 4; ++rp)
                v[4*r+rp] = buf[S6(base + 4*r + rp)];
        inv_group16<4>(v, 0);
#pragma unroll
        for (int k = 0; k < 16; ++k)
            mg[k] = sqrtf(v[k].x*v[k].x + v[k].y*v[k].y) * INV_T;
    }
    __syncthreads();
    float* uf = (float*)buf;
    int rt = ((t & 3) << 6) | (((t >> 2) & 3) << 4) | (((t >> 4) & 3) << 2) | (t >> 6);
#pragma unroll
    for (int r = 0; r < 4; ++r)
#pragma unroll
        for (int rp = 0; rp < 4; ++rp)
            uf[US(rp*1024 + r*256 + rt)] = mg[4*r+rp];
    __syncthreads();
    const int m = t >> 2, s = t & 3;
    float acc = 0.f;
    for (int e = -160 + s; e <= 160; e += 4) {
        int n = (64*m + e) & 4095;
        int a = e < 0 ? -e : e;
        acc += hd[a] * uf[US(n)];
    }
    acc += __shfl_xor(acc, 1);
    acc += __shfl_xor(acc, 2);
    if (s == 0)
        out[(size_t)b * (NPATH * TPRIME) + (size_t)(65 + (n1 << 3) + n2) * TPRIME + m] = acc;
}

extern "C" void kernel_launch(void* const* d_in, const int* in_sizes, int n_in,
                              void* d_out, int out_size, void* d_ws, size_t ws_size,
                              hipStream_t stream) {
    const float* x    = (const float*)d_in[0];
    const float* psi1 = (const float*)d_in[1];
    const float* psi2 = (const float*)d_in[2];
    const float* phi  = (const float*)d_in[3];
    float* out = (float*)d_out;

    const int B = in_sizes[0] / T_LEN;          // 4

    float*  hws = (float*)d_ws;                               // NH floats (pad 4 KiB)
    float2* wsX = (float2*)((char*)d_ws + 4096);
    float2* wsU = (float2*)((char*)d_ws + 4096 + (size_t)B * T_LEN * sizeof(float2));
    float2* Z   = wsU;   // K1 intermediate; clobbered later by pass_b (stream-ordered)

    k1_prep<<<2 * B + 81, 512, 0, stream>>>(x, phi, Z, hws, 2 * B);
    k2_chunk_s0<<<4 * B + 8 * B, 256, 0, stream>>>(Z, x, hws, wsX, out, 4 * B);
    pass_b<<<B * 64, NTH, 0, stream>>>(wsX, psi1, phi, wsU, out);
    k4_med2<<<B * 24, 512, 0, stream>>>(wsU, psi2, hws, out);
    k4_small<<<B * 488, 256, 0, stream>>>(wsU, psi2, hws, out);
}

// Round 24
// 91.089 us; speedup vs baseline: 1.2613x; 1.0047x over previous
//
#include <hip/hip_runtime.h>
#include <math.h>

#define T_LEN   16384          // 4^7
#define NTH     512
#define TPRIME  64
#define NPATH   577            // 1 + 64 + 512
#define INV_T   (1.0f/16384.0f)
#define TWO_PI  6.28318530717958647692f
#define NW      640            // lowpass kernel half-width
#define NH      (NW + 1)
#define C8C     0.92387953251128675613f   // cos(pi/8)
#define C8S     0.38268343236508977173f   // sin(pi/8)

__device__ __forceinline__ int rev4(int i) {
    int r = 0;
#pragma unroll
    for (int p = 0; p < 7; ++p) { r = (r << 2) | (i & 3); i >>= 2; }
    return r;
}
__device__ __forceinline__ int IDX(int i) {
    return i ^ ((i >> 4) & 15) ^ ((i >> 8) & 15);
}
#define S6 IDX
__device__ __forceinline__ int UIDX(int n) {
    return n ^ ((n >> 5) & 31) ^ ((n >> 10) & 31);
}
__device__ __forceinline__ int US(int n) { return n ^ ((n >> 5) & 31); }

// ---------------- butterflies (identical math since R3) --------------------
__device__ __forceinline__ void inv_bf4(float2& A0, float2& A1, float2& A2, float2& A3,
                                        float c1, float s1) {
    float sr = A0.x + A1.x + A2.x + A3.x, si = A0.y + A1.y + A2.y + A3.y;
    float tr = A0.x - A1.y - A2.x + A3.y, ti = A0.y + A1.x - A2.y - A3.x;
    float ur = A0.x - A1.x + A2.x - A3.x, ui = A0.y - A1.y + A2.y - A3.y;
    float vr = A0.x + A1.y - A2.x - A3.y, vi = A0.y - A1.x - A2.y + A3.x;
    float c2 = c1*c1 - s1*s1, s2 = 2.f*c1*s1;
    float c3 = c1*c2 - s1*s2, s3 = c1*s2 + s1*c2;
    A0 = make_float2(sr, si);
    A1 = make_float2(tr*c1 - ti*s1, tr*s1 + ti*c1);
    A2 = make_float2(ur*c2 - ui*s2, ur*s2 + ui*c2);
    A3 = make_float2(vr*c3 - vi*s3, vr*s3 + vi*c3);
}
__device__ __forceinline__ void fwd_bf4(float2& B0, float2& B1, float2& B2, float2& B3,
                                        float c1, float s1) {
    float c2 = c1*c1 - s1*s1, s2 = 2.f*c1*s1;
    float c3 = c1*c2 - s1*s2, s3 = c1*s2 + s1*c2;
    float trr = B1.x*c1 + B1.y*s1, tii = B1.y*c1 - B1.x*s1;
    float urr = B2.x*c2 + B2.y*s2, uii = B2.y*c2 - B2.x*s2;
    float vrr = B3.x*c3 + B3.y*s3, vii = B3.y*c3 - B3.x*s3;
    float s0r = B0.x, s0i = B0.y;
    B0 = make_float2(s0r + trr + urr + vrr, s0i + tii + uii + vii);
    B1 = make_float2(s0r + tii - urr - vii, s0i - trr - uii + vrr);
    B2 = make_float2(s0r - trr + urr - vrr, s0i - tii + uii - vii);
    B3 = make_float2(s0r - tii - urr + vii, s0i + trr - uii - vrr);
}

template<int Q>
__device__ __forceinline__ void inv_group16(float2* v, int jp) {
    float a0 = (float)jp * (TWO_PI / (float)(4 * Q));
    float cw, sw; __sincosf(a0, &sw, &cw);
    float c = cw, s = sw;
#pragma unroll
    for (int rp = 0; rp < 4; ++rp) {
        inv_bf4(v[rp], v[4+rp], v[8+rp], v[12+rp], c, s);
        float cn = c*C8C - s*C8S, sn = c*C8S + s*C8C;
        c = cn; s = sn;
    }
    float b0 = (float)jp * (TWO_PI / (float)Q);
    float cb, sb; __sincosf(b0, &sb, &cb);
#pragma unroll
    for (int r = 0; r < 4; ++r)
        inv_bf4(v[4*r], v[4*r+1], v[4*r+2], v[4*r+3], cb, sb);
}
template<int QA>
__device__ __forceinline__ void fwd_group16(float2* v, int jp) {
    float aA = (float)jp * (TWO_PI / (float)(4 * QA));
    float cA, sA; __sincosf(aA, &sA, &cA);
#pragma unroll
    for (int r = 0; r < 4; ++r)
        fwd_bf4(v[4*r], v[4*r+1], v[4*r+2], v[4*r+3], cA, sA);
    float aB = (float)jp * (TWO_PI / (float)(16 * QA));
    float cB, sB; __sincosf(aB, &sB, &cB);
    float c = cB, s = sB;
#pragma unroll
    for (int rp = 0; rp < 4; ++rp) {
        fwd_bf4(v[rp], v[4+rp], v[8+rp], v[12+rp], c, s);
        float cn = c*C8C - s*C8S, sn = c*C8S + s*C8C;
        c = cn; s = sn;
    }
}

// ===== 512-thread merged passes, sequential groups (R10/R14-proven) ========
template<int LQ>
__device__ void inv_pass16(float2* buf) {
    const int q = 1 << LQ, qp = q >> 2;
    __syncthreads();
#pragma unroll
    for (int it = 0; it < 2; ++it) {
        int g2 = threadIdx.x + it * NTH;
        int jp = g2 & (qp - 1);
        int base = ((g2 >> (LQ - 2)) << (LQ + 2)) | jp;
        float2 v[16];
#pragma unroll
        for (int r = 0; r < 4; ++r)
#pragma unroll
            for (int rp = 0; rp < 4; ++rp)
                v[4*r+rp] = buf[IDX(base + r*q + rp*qp)];
        inv_group16<(1 << LQ)>(v, jp);
#pragma unroll
        for (int r = 0; r < 4; ++r)
#pragma unroll
            for (int rp = 0; rp < 4; ++rp)
                buf[IDX(base + r*q + rp*qp)] = v[4*r+rp];
    }
}

// R24: NO-BARRIER variants for the wave-private middle section of pass_b.
// For LQ in {8,4} (and fwd LQA in {2,6}) every slot group lies inside a
// 1024-slot block owned by ONE wave: block w (it=0) and w+8 (it=1) for
// wave w. Intra-wave LDS RAW ordering is handled by lgkmcnt; the fence
// stops compiler reordering across phases.
template<int LQ>
__device__ void inv_pass16_nb(float2* buf) {
    const int q = 1 << LQ, qp = q >> 2;
#pragma unroll
    for (int it = 0; it < 2; ++it) {
        int g2 = threadIdx.x + it * NTH;
        int jp = g2 & (qp - 1);
        int base = ((g2 >> (LQ - 2)) << (LQ + 2)) | jp;
        float2 v[16];
#pragma unroll
        for (int r = 0; r < 4; ++r)
#pragma unroll
            for (int rp = 0; rp < 4; ++rp)
                v[4*r+rp] = buf[IDX(base + r*q + rp*qp)];
        inv_group16<(1 << LQ)>(v, jp);
#pragma unroll
        for (int r = 0; r < 4; ++r)
#pragma unroll
            for (int rp = 0; rp < 4; ++rp)
                buf[IDX(base + r*q + rp*qp)] = v[4*r+rp];
    }
    asm volatile("" ::: "memory");
}

// merged inverse pass 0 (LQ=12), global src, windowed. R14: unroll 1 on the
// OUTER it-loop only (v declared inside, statically indexed -> registers).
__device__ void inv_pass16_g(const float2* __restrict__ src, const float* __restrict__ filt,
                             float2* buf, int clo, int chi) {
#pragma unroll 1
    for (int it = 0; it < 2; ++it) {
        int jp = threadIdx.x + it * NTH;
        float2 v[16];
#pragma unroll
        for (int r = 0; r < 4; ++r)
#pragma unroll
            for (int rp = 0; rp < 4; ++rp) {
                int ch = 4*r + rp;
                if (ch >= clo && ch <= chi) {
                    int i = jp + r*4096 + rp*1024;
                    float2 a = src[i]; float p = filt[i];
                    v[4*r+rp] = make_float2(a.x*p, a.y*p);
                } else {
                    v[4*r+rp] = make_float2(0.f, 0.f);
                }
            }
        inv_group16<4096>(v, jp);
#pragma unroll
        for (int r = 0; r < 4; ++r)
#pragma unroll
            for (int rp = 0; rp < 4; ++rp)
                buf[IDX(jp + r*4096 + rp*1024)] = v[4*r+rp];
        asm volatile("" ::: "memory");
    }
}

// R24: wave-private FUSED inv-final + modulus + fwd-first. Thread t handles
// quadruplets ((t&3)+4k) of 64-groups (t>>2) and (t>>2)+128 — both inside
// its wave's 1024-blocks (w, w+8). Coverage: 512 thr x 8 quads = 4096 ✓.
__device__ void mod_fwd4_wp(float2* buf) {
#pragma unroll
    for (int it = 0; it < 2; ++it) {
        int g = (threadIdx.x >> 2) + it * 128;
#pragma unroll
        for (int k = 0; k < 4; ++k) {
            int base = g * 64 + ((threadIdx.x & 3) + k * 4) * 4;
            float2 a0 = buf[IDX(base)], a1 = buf[IDX(base+1)], a2 = buf[IDX(base+2)], a3 = buf[IDX(base+3)];
            inv_bf4(a0, a1, a2, a3, 1.0f, 0.0f);
            float2 b0 = make_float2(sqrtf(a0.x*a0.x + a0.y*a0.y) * INV_T, 0.f);
            float2 b1 = make_float2(sqrtf(a1.x*a1.x + a1.y*a1.y) * INV_T, 0.f);
            float2 b2 = make_float2(sqrtf(a2.x*a2.x + a2.y*a2.y) * INV_T, 0.f);
            float2 b3 = make_float2(sqrtf(a3.x*a3.x + a3.y*a3.y) * INV_T, 0.f);
            fwd_bf4(b0, b1, b2, b3, 1.0f, 0.0f);
            buf[IDX(base)] = b0; buf[IDX(base+1)] = b1; buf[IDX(base+2)] = b2; buf[IDX(base+3)] = b3;
        }
    }
    asm volatile("" ::: "memory");
}

template<int LQA>
__device__ void fwd_pass16_nb(float2* buf) {
    const int qA = 1 << LQA, qB = 4 * qA;
#pragma unroll
    for (int it = 0; it < 2; ++it) {
        int g2 = threadIdx.x + it * NTH;
        int jp = g2 & (qA - 1);
        int base = ((g2 >> LQA) << (LQA + 4)) | jp;
        float2 v[16];
#pragma unroll
        for (int r = 0; r < 4; ++r)
#pragma unroll
            for (int rp = 0; rp < 4; ++rp)
                v[4*r+rp] = buf[IDX(base + r*qB + rp*qA)];
        fwd_group16<(1 << LQA)>(v, jp);
#pragma unroll
        for (int r = 0; r < 4; ++r)
#pragma unroll
            for (int rp = 0; rp < 4; ++rp)
                buf[IDX(base + r*qB + rp*qA)] = v[4*r+rp];
    }
    asm volatile("" ::: "memory");
}

// last forward merged pass (LQA=10): windowed global store + zs staging
__device__ void fwd_last_store_zs(float2* buf, float2* __restrict__ gout, int nchunks,
                                  float2* zs) {
    __syncthreads();
#pragma unroll 1
    for (int it = 0; it < 2; ++it) {
        int jp = threadIdx.x + it * NTH;
        float2 v[16];
#pragma unroll
        for (int r = 0; r < 4; ++r)
#pragma unroll
            for (int rp = 0; rp < 4; ++rp)
                v[4*r+rp] = buf[IDX(jp + r*4096 + rp*1024)];
        fwd_group16<1024>(v, jp);
        if (it == 0 && jp < 124) zs[jp] = v[0];   // bin k = jp (r=rp=0)
#pragma unroll
        for (int r = 0; r < 4; ++r)
#pragma unroll
            for (int rp = 0; rp < 4; ++rp) {
                int ch = 4*r + rp;
                if (ch < nchunks)
                    gout[jp + r*4096 + rp*1024] = v[4*r+rp];
            }
        asm volatile("" ::: "memory");
    }
}

// ======================= K1: pass_a L12 + hconv ============================
__global__ __launch_bounds__(512) void k1_prep(const float* __restrict__ x,
                                               const float* __restrict__ phi,
                                               float2* __restrict__ Z,
                                               float* __restrict__ hws,
                                               int B2) {
    const int bi = blockIdx.x;
    if (bi < B2) {
        const int b = bi >> 1;
        const int jp = ((bi & 1) << 9) | threadIdx.x;   // 0..1023
        const float* xb = x + (size_t)b * T_LEN;
        float2* Zb = Z + (size_t)b * T_LEN;
        float2 v[16];
#pragma unroll
        for (int r = 0; r < 4; ++r)
#pragma unroll
            for (int rp = 0; rp < 4; ++rp)
                v[4*r+rp] = make_float2(xb[jp + r*4096 + rp*1024], 0.f);
        inv_group16<4096>(v, jp);
#pragma unroll
        for (int r = 0; r < 4; ++r)
#pragma unroll
            for (int rp = 0; rp < 4; ++rp)
                Zb[jp + r*4096 + rp*1024] = v[4*r+rp];
    } else {
        const int d = (bi - B2) * 8 + (threadIdx.x >> 6);
        const int l = threadIdx.x & 63;
        float p = 0.f;
#pragma unroll
        for (int j = 0; j < 8; ++j) {
            int w = l + 64 * j;                   // 0..511
            int k = (w < 256) ? w : (15872 + w);  // [0,255] U [16128,16383]
            int r = (k * d) & (T_LEN - 1);
            p += phi[k] * __cosf((float)r * (TWO_PI / (float)T_LEN));
        }
        p += __shfl_xor(p, 1);  p += __shfl_xor(p, 2);  p += __shfl_xor(p, 4);
        p += __shfl_xor(p, 8);  p += __shfl_xor(p, 16); p += __shfl_xor(p, 32);
        if (l == 0 && d <= NW) hws[d] = p * INV_T;
    }
}

// ================= K2: pass_a chunk tails + S0 =============================
__global__ __launch_bounds__(256) void k2_chunk_s0(const float2* __restrict__ Z,
                                                   const float* __restrict__ x,
                                                   const float* __restrict__ hws,
                                                   float2* __restrict__ wsX,
                                                   float* __restrict__ out,
                                                   int B4) {
    __shared__ float2 lds[4096];
    __shared__ float hl[NH];
    const int bi = blockIdx.x;
    if (bi < B4) {
        const int b = bi >> 2;
        const int c0 = (bi & 3) << 12;
        const float2* Zb = Z + (size_t)b * T_LEN + c0;
        for (int i = threadIdx.x; i < 4096; i += 256) lds[IDX(i)] = Zb[i];
        {
            __syncthreads();
            int g = threadIdx.x;
            int jp = g & 63, base = ((g >> 6) << 10) | jp;
            float2 v[16];
#pragma unroll
            for (int r = 0; r < 4; ++r)
#pragma unroll
                for (int rp = 0; rp < 4; ++rp)
                    v[4*r+rp] = lds[IDX(base + r*256 + rp*64)];
            inv_group16<256>(v, jp);
#pragma unroll
            for (int r = 0; r < 4; ++r)
#pragma unroll
                for (int rp = 0; rp < 4; ++rp)
                    lds[IDX(base + r*256 + rp*64)] = v[4*r+rp];
        }
        {
            __syncthreads();
            int g = threadIdx.x;
            int jp = g & 3, base = ((g >> 2) << 6) | jp;
            float2 v[16];
#pragma unroll
            for (int r = 0; r < 4; ++r)
#pragma unroll
                for (int rp = 0; rp < 4; ++rp)
                    v[4*r+rp] = lds[IDX(base + r*16 + rp*4)];
            inv_group16<16>(v, jp);
#pragma unroll
            for (int r = 0; r < 4; ++r)
#pragma unroll
                for (int rp = 0; rp < 4; ++rp)
                    lds[IDX(base + r*16 + rp*4)] = v[4*r+rp];
        }
        __syncthreads();
        float2* W = wsX + (size_t)b * T_LEN;
#pragma unroll
        for (int it = 0; it < 4; ++it) {
            int bl = (threadIdx.x + it * 256) << 2;
            float2 a0 = lds[IDX(bl)], a1 = lds[IDX(bl+1)], a2 = lds[IDX(bl+2)], a3 = lds[IDX(bl+3)];
            inv_bf4(a0, a1, a2, a3, 1.0f, 0.0f);
            int rb = rev4(c0 + bl);
            W[rb]         = make_float2(a0.x, -a0.y);
            W[rb + 4096]  = make_float2(a1.x, -a1.y);
            W[rb + 8192]  = make_float2(a2.x, -a2.y);
            W[rb + 12288] = make_float2(a3.x, -a3.y);
        }
    } else {
        const int q = bi - B4;
        const int b = q >> 3;
        const int m0 = (q & 7) << 3;
        for (int i = threadIdx.x; i < NH; i += 256) hl[i] = hws[i];
        __syncthreads();
        const float* xb = x + (size_t)b * T_LEN;
        const int m = m0 + (threadIdx.x >> 5);
        const int s = threadIdx.x & 31;
        const int c = m << 8;
        float acc = 0.f;
        for (int e = -NW + s; e <= NW; e += 32) {
            int n = (c + e) & (T_LEN - 1);
            int a = e < 0 ? -e : e;
            acc += hl[a] * xb[n];
        }
        acc += __shfl_xor(acc, 1);  acc += __shfl_xor(acc, 2);
        acc += __shfl_xor(acc, 4);  acc += __shfl_xor(acc, 8);
        acc += __shfl_xor(acc, 16);
        if (s == 0) out[(size_t)b * (NPATH * TPRIME) + m] = acc;
    }
}

// ================= K3: pass B (monolithic; R24 wave-private middle) ========
__global__ __launch_bounds__(NTH)
__attribute__((amdgpu_waves_per_eu(1, 2)))
void pass_b(const float2* __restrict__ wsX,
            const float* __restrict__ psi1,
            const float* __restrict__ phi,
            float2* __restrict__ wsU,
            float* __restrict__ out) {
    __shared__ float2 buf[T_LEN];
    __shared__ float2 zs[128];
    const int blk = blockIdx.x;
    const int b = blk >> 6, n1 = blk & 63;
    float xi1T = 5734.4f * exp2f(-(float)n1 / 8.0f);
    int clo = (int)(0.40f * xi1T) >> 10;
    int chi = ((int)(1.60f * xi1T)) >> 10; if (chi > 15) chi = 15;
    inv_pass16_g(wsX + (size_t)b * T_LEN, psi1 + (size_t)n1 * T_LEN, buf, clo, chi);
    __syncthreads();                    // L12 output crosses waves
    // Wave-private middle section: every phase below stays inside the
    // 1024-blocks {w, w+8} owned by wave w. No inter-wave barriers.
    inv_pass16_nb<8>(buf);
    inv_pass16_nb<4>(buf);
    mod_fwd4_wp(buf);
    fwd_pass16_nb<2>(buf);
    fwd_pass16_nb<6>(buf);
    const int n2min = (n1 >> 3) + 1;
    int nch = 0;
    if (n2min <= 7) {
        int S = 24084 >> n2min;
        nch = (S >> 10) + 1; if (nch > 10) nch = 10;
    }
    fwd_last_store_zs(buf, wsU + (size_t)blk * T_LEN, nch, zs);   // leading barrier
    __syncthreads();
    const int m = threadIdx.x >> 3;
    const int s = threadIdx.x & 7;
    float acc = 0.f;
    for (int k = 1 + s; k < 124; k += 8) {
        float ph = phi[k];
        float2 z = zs[k];
        float ang = (float)((k * m) & 63) * (TWO_PI / 64.0f);
        float sn, cs; __sincosf(ang, &sn, &cs);
        acc += 2.0f * ph * (z.x * cs - z.y * sn);
    }
    acc += __shfl_xor(acc, 1);
    acc += __shfl_xor(acc, 2);
    acc += __shfl_xor(acc, 4);
    if (s == 0) {
        acc += zs[0].x * phi[0];
        out[(size_t)b * (NPATH * TPRIME) + (size_t)(1 + n1) * TPRIME + m] = acc * INV_T;
    }
}

// ====== K4a: med (n2 in {1,2}), 512 threads, h-halves IN PARALLEL ==========
__global__ __launch_bounds__(512) void k4_med2(const float2* __restrict__ wsU,
                                               const float* __restrict__ psi2,
                                               const float* __restrict__ hws,
                                               float* __restrict__ out) {
    __shared__ float2 sc2[8192];    // 64 KB: two 4096-slot halves
    __shared__ float h2s[321];
    const int tj = threadIdx.x;
    const int hh = tj >> 8, t = tj & 255;
    const int idx = blockIdx.x % 24, b = blockIdx.x / 24;
    const int n2 = (idx < 8) ? 1 : 2;
    const int n1 = (idx < 8) ? idx : idx - 8;
    for (int i = tj; i < 321; i += 512) h2s[i] = 2.0f * hws[2 * i];
    float2* sc = sc2 + (hh << 12);
    const float2* Ub = wsU + (size_t)((b << 6) | n1) * T_LEN;
    const float* p2 = psi2 + (size_t)n2 * T_LEN;
    const int lim = (n2 == 1) ? 10240 : 6144;
    float2 v[16];
#pragma unroll
    for (int r = 0; r < 4; ++r) {
#pragma unroll
        for (int rp = 0; rp < 4; ++rp) {
            int i = t + r*1024 + rp*256;
            float2 y0 = Ub[i]; float q0 = p2[i];
            float ar = y0.x * q0, ai = y0.y * q0;
            if (i + 4096 < lim) {
                float2 y1 = Ub[i + 4096]; float q1 = p2[i + 4096];
                if (hh == 0) { ar += y1.x*q1; ai += y1.y*q1; }
                else         { ar -= y1.x*q1; ai -= y1.y*q1; }
            }
            if (i + 8192 < lim) {
                float2 y2 = Ub[i + 8192]; float q2 = p2[i + 8192];
                ar += y2.x*q2; ai += y2.y*q2;
            }
            if (hh == 1) {  // twiddle e^{+2 pi i j / 8192}
                float ang = (float)i * (TWO_PI / 8192.0f);
                float sn, cs; __sincosf(ang, &sn, &cs);
                float nr = ar*cs - ai*sn, ni = ar*sn + ai*cs;
                ar = nr; ai = ni;
            }
            v[4*r+rp] = make_float2(ar, ai);
        }
        asm volatile("" ::: "memory");
    }
    inv_group16<1024>(v, t);
#pragma unroll
    for (int r = 0; r < 4; ++r)
#pragma unroll
        for (int rp = 0; rp < 4; ++rp)
            sc[S6(t + r*1024 + rp*256)] = v[4*r+rp];
    __syncthreads();
    {
        int jp = t & 15, base = ((t >> 4) << 8) | jp;
#pragma unroll
        for (int r = 0; r < 4; ++r)
#pragma unroll
            for (int rp = 0; rp < 4; ++rp)
                v[4*r+rp] = sc[S6(base + r*64 + rp*16)];
        inv_group16<64>(v, jp);
#pragma unroll
        for (int r = 0; r < 4; ++r)
#pragma unroll
            for (int rp = 0; rp < 4; ++rp)
                sc[S6(base + r*64 + rp*16)] = v[4*r+rp];
    }
    __syncthreads();
    float mg[16];
    {
        int base = t << 4;
#pragma unroll
        for (int r = 0; r < 4; ++r)
#pragma unroll
            for (int rp = 0; rp < 4; ++rp)
                v[4*r+rp] = sc[S6(base + 4*r + rp)];
        inv_group16<4>(v, 0);
#pragma unroll
        for (int k = 0; k < 16; ++k)
            mg[k] = sqrtf(v[k].x*v[k].x + v[k].y*v[k].y) * INV_T;
    }
    __syncthreads();    // all sc reads done before float reuse
    float* u8s = (float*)sc2;   // first 32 KB of sc2 (8192 floats)
    int rt = ((t & 3) << 6) | (((t >> 2) & 3) << 4) | (((t >> 4) & 3) << 2) | (t >> 6);
#pragma unroll
    for (int r = 0; r < 4; ++r)
#pragma unroll
        for (int rp = 0; rp < 4; ++rp) {
            int pos = rp*1024 + r*256 + rt;
            u8s[UIDX(2 * pos + hh)] = mg[4*r+rp];
        }
    __syncthreads();
    // lowpass on 8192 (stride-2) grid: 8 lanes per output
    const int m = tj >> 3, s = tj & 7;
    float acc = 0.f;
    for (int e = -320 + s; e <= 320; e += 8) {
        int n = (128*m + e) & 8191;
        int a = e < 0 ? -e : e;
        acc += h2s[a] * u8s[UIDX(n)];
    }
    acc += __shfl_xor(acc, 1);
    acc += __shfl_xor(acc, 2);
    acc += __shfl_xor(acc, 4);
    if (s == 0)
        out[(size_t)b * (NPATH * TPRIME) + (size_t)(65 + (n1 << 3) + n2) * TPRIME + m] = acc;
}

// ======= K4b: small (n2>=3, 200/batch) + zero-invalid (288/batch) ==========
__global__ __launch_bounds__(256) void k4_small(const float2* __restrict__ wsU,
                                                const float* __restrict__ psi2,
                                                const float* __restrict__ hws,
                                                float* __restrict__ out) {
    __shared__ float2 buf[4096];
    __shared__ float hd[161];
    const int t = threadIdx.x;
    const int idx = blockIdx.x % 488, b = blockIdx.x / 488;

    if (idx >= 200) {               // ---- zero block: one invalid S2 path ----
        int z = idx - 200;          // 0..287
        int g = 0, cum = 0;
#pragma unroll
        for (int gg = 0; gg < 8; ++gg) {
            int c = 8 * (gg + 1);
            if (z >= cum + c) { cum += c; g = gg + 1; }
        }
        int zz = z - cum;
        int n1 = g * 8 + zz / (g + 1);
        int n2 = zz % (g + 1);
        if (t < TPRIME)
            out[(size_t)b * (NPATH * TPRIME) + (size_t)(65 + (n1 << 3) + n2) * TPRIME + t] = 0.f;
        return;
    }

    const int p = idx;
    int n1, n2;
    if      (p < 24)  { n2 = 3; n1 = p; }
    else if (p < 56)  { n2 = 4; n1 = p - 24; }
    else if (p < 96)  { n2 = 5; n1 = p - 56; }
    else if (p < 144) { n2 = 6; n1 = p - 96; }
    else              { n2 = 7; n1 = p - 144; }
    if (t < 161) hd[t] = 4.0f * hws[4 * t];
    const int kc = ((((int)(24084.0f * exp2f(-(float)n2))) >> 10) + 1) << 2;
    const float2* Ub = wsU + (size_t)((b << 6) | n1) * T_LEN;
    const float* p2 = psi2 + (size_t)n2 * T_LEN;
    float2 v[16];
#pragma unroll
    for (int r = 0; r < 4; ++r)
#pragma unroll
        for (int rp = 0; rp < 4; ++rp) {
            int ch = 4*r + rp;
            if (ch < kc) {
                int i = t + r*1024 + rp*256;
                float2 u = Ub[i]; float pp = p2[i];
                v[4*r+rp] = make_float2(u.x*pp, u.y*pp);
            } else {
                v[4*r+rp] = make_float2(0.f, 0.f);
            }
        }
    inv_group16<1024>(v, t);
#pragma unroll
    for (int r = 0; r < 4; ++r)
#pragma unroll
        for (int rp = 0; rp < 4; ++rp)
            buf[S6(t + r*1024 + rp*256)] = v[4*r+rp];
    __syncthreads();
    {
        int jp = t & 15, base = ((t >> 4) << 8) | jp;
#pragma unroll
        for (int r = 0; r < 4; ++r)
#pragma unroll
            for (int rp = 0; rp < 4; ++rp)
                v[4*r+rp] = buf[S6(base + r*64 + rp*16)];
        inv_group16<64>(v, jp);
#pragma unroll
        for (int r = 0; r < 4; ++r)
#pragma unroll
            for (int rp = 0; rp < 4; ++rp)
                buf[S6(base + r*64 + rp*16)] = v[4*r+rp];
    }
    __syncthreads();
    float mg[16];
    {
        int base = t << 4;
#pragma unroll
        for (int r = 0; r < 4; ++r)
#pragma unroll
            for (int rp = 0; rp < 4; ++rp)
                v[4*r+rp] = buf[S6(base + 4*r + rp)];
        inv_group16<4>(v, 0);
#pragma unroll
        for (int k = 0; k < 16; ++k)
            mg[k] = sqrtf(v[k].x*v[k].x + v[k].y*v[k].y) * INV_T;
    }
    __syncthreads();
    float* uf = (float*)buf;
    int rt = ((t & 3) << 6) | (((t >> 2) & 3) << 4) | (((t >> 4) & 3) << 2) | (t >> 6);
#pragma unroll
    for (int r = 0; r < 4; ++r)
#pragma unroll
        for (int rp = 0; rp < 4; ++rp)
            uf[US(rp*1024 + r*256 + rt)] = mg[4*r+rp];
    __syncthreads();
    const int m = t >> 2, s = t & 3;
    float acc = 0.f;
    for (int e = -160 + s; e <= 160; e += 4) {
        int n = (64*m + e) & 4095;
        int a = e < 0 ? -e : e;
        acc += hd[a] * uf[US(n)];
    }
    acc += __shfl_xor(acc, 1);
    acc += __shfl_xor(acc, 2);
    if (s == 0)
        out[(size_t)b * (NPATH * TPRIME) + (size_t)(65 + (n1 << 3) + n2) * TPRIME + m] = acc;
}

extern "C" void kernel_launch(void* const* d_in, const int* in_sizes, int n_in,
                              void* d_out, int out_size, void* d_ws, size_t ws_size,
                              hipStream_t stream) {
    const float* x    = (const float*)d_in[0];
    const float* psi1 = (const float*)d_in[1];
    const float* psi2 = (const float*)d_in[2];
    const float* phi  = (const float*)d_in[3];
    float* out = (float*)d_out;

    const int B = in_sizes[0] / T_LEN;          // 4

    float*  hws = (float*)d_ws;                               // NH floats (pad 4 KiB)
    float2* wsX = (float2*)((char*)d_ws + 4096);
    float2* wsU = (float2*)((char*)d_ws + 4096 + (size_t)B * T_LEN * sizeof(float2));
    float2* Z   = wsU;   // K1 intermediate; clobbered later by pass_b (stream-ordered)

    k1_prep<<<2 * B + 81, 512, 0, stream>>>(x, phi, Z, hws, 2 * B);
    k2_chunk_s0<<<4 * B + 8 * B, 256, 0, stream>>>(Z, x, hws, wsX, out, 4 * B);
    pass_b<<<B * 64, NTH, 0, stream>>>(wsX, psi1, phi, wsU, out);
    k4_med2<<<B * 24, 512, 0, stream>>>(wsU, psi2, hws, out);
    k4_small<<<B * 488, 256, 0, stream>>>(wsU, psi2, hws, out);
}